// Round 1
// baseline (858.756 us; speedup 1.0000x reference)
//
#include <hip/hip_runtime.h>
#include <math.h>

#define DCLS 32000
#define NQ   (DCLS / 4)      // 8000 float4 per row
#define BLK  256
#define NW   (BLK / 64)      // waves per block
#define CAP  6144            // compact-list capacity (24 KB LDS)

// ---------------- kernel 1: per-row max of Xa = 0.5*X ----------------
__global__ __launch_bounds__(BLK)
void rowmax_k(const float* __restrict__ X, float* __restrict__ rmax) {
  const int row = blockIdx.x;
  const float4* __restrict__ Xr =
      reinterpret_cast<const float4*>(X + (size_t)row * DCLS);
  float m = -INFINITY;
  for (int i = threadIdx.x; i < NQ; i += BLK) {
    float4 v = Xr[i];
    m = fmaxf(m, fmaxf(fmaxf(v.x, v.y), fmaxf(v.z, v.w)));
  }
#pragma unroll
  for (int o = 32; o > 0; o >>= 1) m = fmaxf(m, __shfl_down(m, o, 64));
  __shared__ float sm[NW];
  const int lane = threadIdx.x & 63, wid = threadIdx.x >> 6;
  if (lane == 0) sm[wid] = m;
  __syncthreads();
  if (threadIdx.x == 0) {
    float mm = sm[0];
#pragma unroll
    for (int w = 1; w < NW; ++w) mm = fmaxf(mm, sm[w]);
    rmax[row] = 0.5f * mm;  // max of Xa (0.5* is monotone & exact)
  }
}

// ------- kernel 2: compact actives, 50-iter bisection, loss -------
__global__ __launch_bounds__(BLK)
void entmax_loss_k(const float* __restrict__ X, const int* __restrict__ tgt,
                   const float* __restrict__ rmax, float* __restrict__ out,
                   float inv_n) {
  const int row = blockIdx.x;
  const size_t base = (size_t)row * DCLS;
  const float4* __restrict__ Xr = reinterpret_cast<const float4*>(X + base);
  const float maxv = rmax[row];        // max of Xa
  const float tau0 = maxv - 1.0f;      // tau_lo initial; only Xa > tau0 matter

  __shared__ float vals[CAP];
  __shared__ int cnt;
  __shared__ float red[2][NW];
  if (threadIdx.x == 0) cnt = 0;
  __syncthreads();

  // gather actives (Xa_j > tau0) into LDS compact list
  for (int i = threadIdx.x; i < NQ; i += BLK) {
    float4 v = Xr[i];
    float a0 = 0.5f * v.x, a1 = 0.5f * v.y, a2 = 0.5f * v.z, a3 = 0.5f * v.w;
    if (a0 > tau0) { int p = atomicAdd(&cnt, 1); if (p < CAP) vals[p] = a0; }
    if (a1 > tau0) { int p = atomicAdd(&cnt, 1); if (p < CAP) vals[p] = a1; }
    if (a2 > tau0) { int p = atomicAdd(&cnt, 1); if (p < CAP) vals[p] = a2; }
    if (a3 > tau0) { int p = atomicAdd(&cnt, 1); if (p < CAP) vals[p] = a3; }
  }
  __syncthreads();
  const int n = cnt;
  const bool ovf = (n > CAP);   // general-correctness fallback path
  const int lane = threadIdx.x & 63, wid = threadIdx.x >> 6;

  int callidx = 0;
  // block-wide sum of max(v - tau, 0)^2, broadcast to all threads.
  // One barrier per call via parity double-buffered partials.
  auto fsum = [&](float tau) -> float {
    float s = 0.0f;
    if (!ovf) {
      for (int i = threadIdx.x; i < n; i += BLK) {
        float z = vals[i] - tau;
        if (z > 0.0f) s = fmaf(z, z, s);
      }
    } else {
      for (int i = threadIdx.x; i < NQ; i += BLK) {
        float4 v = Xr[i];
        float z;
        z = fmaxf(0.5f * v.x - tau, 0.0f); s = fmaf(z, z, s);
        z = fmaxf(0.5f * v.y - tau, 0.0f); s = fmaf(z, z, s);
        z = fmaxf(0.5f * v.z - tau, 0.0f); s = fmaf(z, z, s);
        z = fmaxf(0.5f * v.w - tau, 0.0f); s = fmaf(z, z, s);
      }
    }
#pragma unroll
    for (int o = 32; o > 0; o >>= 1) s += __shfl_down(s, o, 64);
    const int par = callidx & 1;
    ++callidx;
    if (lane == 0) red[par][wid] = s;
    __syncthreads();
    float t = red[par][0];
#pragma unroll
    for (int w = 1; w < NW; ++w) t += red[par][w];
    return t;
  };

  // bisection — exact replica of the reference recurrence in fp32
  const float tau_hi = maxv - 0.005590169943749474f;  // (1/32000)^(alpha-1)
  float tau_lo = tau0;
  float dm = tau_hi - tau_lo;
  const float f_lo = fsum(tau_lo) - 1.0f;
  float tau_m = tau_lo;
  for (int it = 0; it < 50; ++it) {
    dm *= 0.5f;
    tau_m = tau_lo + dm;
    const float f_m = fsum(tau_m) - 1.0f;
    if (f_m * f_lo >= 0.0f) tau_lo = tau_m;   // block-uniform
  }

  // final sums at last midpoint tau_m:
  //   S  = sum z^2           (p_raw sum)
  //   S3 = sum z^3           (= sum p_raw^1.5)
  //   SX = sum z^2 * Xa      (p_raw dot Xa; X = 2*Xa exactly)
  float s = 0.0f, s3 = 0.0f, sx = 0.0f;
  if (!ovf) {
    for (int i = threadIdx.x; i < n; i += BLK) {
      float a = vals[i];
      float z = a - tau_m;
      if (z > 0.0f) {
        float q = z * z;
        s += q;
        s3 = fmaf(q, z, s3);
        sx = fmaf(q, a, sx);
      }
    }
  } else {
    for (int i = threadIdx.x; i < NQ; i += BLK) {
      float4 v = Xr[i];
      float a[4] = {0.5f * v.x, 0.5f * v.y, 0.5f * v.z, 0.5f * v.w};
#pragma unroll
      for (int k = 0; k < 4; ++k) {
        float z = a[k] - tau_m;
        if (z > 0.0f) {
          float q = z * z;
          s += q;
          s3 = fmaf(q, z, s3);
          sx = fmaf(q, a[k], sx);
        }
      }
    }
  }
#pragma unroll
  for (int o = 32; o > 0; o >>= 1) {
    s  += __shfl_down(s,  o, 64);
    s3 += __shfl_down(s3, o, 64);
    sx += __shfl_down(sx, o, 64);
  }
  __shared__ float r3[3][NW];
  if (lane == 0) { r3[0][wid] = s; r3[1][wid] = s3; r3[2][wid] = sx; }
  __syncthreads();
  if (threadIdx.x == 0) {
    float S = 0.0f, S3 = 0.0f, SX = 0.0f;
#pragma unroll
    for (int w = 0; w < NW; ++w) { S += r3[0][w]; S3 += r3[1][w]; SX += r3[2][w]; }
    // omega = (1 - sum p^1.5) / (alpha*(alpha-1)) with p = z^2/S
    const float omega = (1.0f - S3 / (S * sqrtf(S))) * (1.0f / 0.75f);
    const float Xt = X[base + (size_t)tgt[row]];
    const float loss = omega + 2.0f * SX / S - Xt;
    atomicAdd(out, loss * inv_n);
  }
}

extern "C" void kernel_launch(void* const* d_in, const int* in_sizes, int n_in,
                              void* d_out, int out_size, void* d_ws, size_t ws_size,
                              hipStream_t stream) {
  const float* X = (const float*)d_in[0];
  const int* tgt = (const int*)d_in[1];
  float* out = (float*)d_out;
  const int nrows = in_sizes[1];          // 4096 targets = row count
  float* rmax = (float*)d_ws;             // nrows floats of scratch

  hipMemsetAsync(d_out, 0, sizeof(float), stream);
  rowmax_k<<<nrows, BLK, 0, stream>>>(X, rmax);
  entmax_loss_k<<<nrows, BLK, 0, stream>>>(X, tgt, rmax, out, 1.0f / (float)nrows);
}